// Round 3
// baseline (82.569 us; speedup 1.0000x reference)
//
#include <hip/hip_runtime.h>

#define OUTN 512
#define NCTL 64
#define BATCH 16

// One block per (b, u) output row; 256 threads = 4 waves; fully wave-synchronous
// (no __syncthreads). Each wave:
//   Phase 1: private A[w][n][c] = sum_r Nu[u][r]*ctrl[b][su-3+r][n][c] (1KB/wave,
//            redundant across waves; ctrl is L2-resident so 4x reads are cheap)
//   Phase 2: lane l handles adjacent v-points v=2t,2t+1; results staged in
//            per-wave LDS (1536B contiguous per wave)
//   Flush:   aligned float4 stores, 96 float4 per wave.
// Wave-internal LDS RAW ordering is guaranteed by HW (in-order LDS pipe per
// wave); __builtin_amdgcn_wave_barrier() only pins compiler scheduling.
__global__ __launch_bounds__(256) void surfeval_kernel(
    const float* __restrict__ ctrl,   // (B,64,64,4)
    const int*   __restrict__ uspan,  // (512)
    const int*   __restrict__ vspan,  // (512)
    const float* __restrict__ Nu,     // (512,4)
    const float* __restrict__ Nv,     // (512,4)
    float*       __restrict__ out)    // (B,512,512,3)
{
    __shared__ float A[4][NCTL][4];     // 4 KB: per-wave u-contracted row
    __shared__ float S[4][128 * 3];     // 6 KB: per-wave output staging

    const int u = blockIdx.x;
    const int b = blockIdx.y;
    const int t = threadIdx.x;
    const int w = t >> 6;
    const int l = t & 63;

    // ---- Prefetch phase-2 inputs (independent of phase 1) ----
    const int v0 = 2 * t;
    const int v1 = v0 + 1;
    const int sv0 = vspan[v0];
    const int sv1 = vspan[v1];
    const float4 nv0 = ((const float4*)Nv)[v0];
    const float4 nv1 = ((const float4*)Nv)[v1];

    const int su = uspan[u];
    const float4 nu = ((const float4*)Nu)[u];

    // ---- Phase 1 (per-wave): lane l computes A[w][l][0..3] ----
    {
        const float4* crow =
            (const float4*)(ctrl + ((size_t)b * NCTL + (size_t)(su - 3)) * (NCTL * 4)) + l;
        const float4 r0 = crow[0];
        const float4 r1 = crow[NCTL];
        const float4 r2 = crow[2 * NCTL];
        const float4 r3 = crow[3 * NCTL];
        float4 a;
        a.x = nu.x * r0.x + nu.y * r1.x + nu.z * r2.x + nu.w * r3.x;
        a.y = nu.x * r0.y + nu.y * r1.y + nu.z * r2.y + nu.w * r3.y;
        a.z = nu.x * r0.z + nu.y * r1.z + nu.z * r2.z + nu.w * r3.z;
        a.w = nu.x * r0.w + nu.y * r1.w + nu.z * r2.w + nu.w * r3.w;
        ((float4*)A[w])[l] = a;
    }
    __builtin_amdgcn_wave_barrier();

    // ---- Phase 2: two adjacent v-points per lane, staged to LDS ----
    {
        const float4* Af = (const float4*)(&A[w][sv0 - 3][0]);
        const float4 s0 = Af[0], s1 = Af[1], s2 = Af[2], s3 = Af[3];
        const float sx = nv0.x * s0.x + nv0.y * s1.x + nv0.z * s2.x + nv0.w * s3.x;
        const float sy = nv0.x * s0.y + nv0.y * s1.y + nv0.z * s2.y + nv0.w * s3.y;
        const float sz = nv0.x * s0.z + nv0.y * s1.z + nv0.z * s2.z + nv0.w * s3.z;
        const float sw = nv0.x * s0.w + nv0.y * s1.w + nv0.z * s2.w + nv0.w * s3.w;
        const float inv = 1.0f / sw;
        S[w][l * 6 + 0] = sx * inv;
        S[w][l * 6 + 1] = sy * inv;
        S[w][l * 6 + 2] = sz * inv;
    }
    {
        const float4* Af = (const float4*)(&A[w][sv1 - 3][0]);
        const float4 s0 = Af[0], s1 = Af[1], s2 = Af[2], s3 = Af[3];
        const float sx = nv1.x * s0.x + nv1.y * s1.x + nv1.z * s2.x + nv1.w * s3.x;
        const float sy = nv1.x * s0.y + nv1.y * s1.y + nv1.z * s2.y + nv1.w * s3.y;
        const float sz = nv1.x * s0.z + nv1.y * s1.z + nv1.z * s2.z + nv1.w * s3.z;
        const float sw = nv1.x * s0.w + nv1.y * s1.w + nv1.z * s2.w + nv1.w * s3.w;
        const float inv = 1.0f / sw;
        S[w][l * 6 + 3] = sx * inv;
        S[w][l * 6 + 4] = sy * inv;
        S[w][l * 6 + 5] = sz * inv;
    }
    __builtin_amdgcn_wave_barrier();

    // ---- Flush: wave w owns 1536B contiguous = 96 float4 ----
    {
        float* orow = out + ((size_t)b * OUTN + (size_t)u) * (OUTN * 3);
        float4* og = (float4*)orow + 96 * w;
        const float4* sg = (const float4*)S[w];
        og[l] = sg[l];
        if (l < 32) og[64 + l] = sg[64 + l];
    }
}

extern "C" void kernel_launch(void* const* d_in, const int* in_sizes, int n_in,
                              void* d_out, int out_size, void* d_ws, size_t ws_size,
                              hipStream_t stream) {
    const float* ctrl  = (const float*)d_in[0];
    const int*   uspan = (const int*)d_in[1];
    const int*   vspan = (const int*)d_in[2];
    const float* Nu    = (const float*)d_in[3];
    const float* Nv    = (const float*)d_in[4];
    float* out = (float*)d_out;

    dim3 grid(OUTN, BATCH);
    surfeval_kernel<<<grid, 256, 0, stream>>>(ctrl, uspan, vspan, Nu, Nv, out);
}